// Round 6
// baseline (237.405 us; speedup 1.0000x reference)
//
#include <hip/hip_runtime.h>

// Attention over channel dim: B=16, HW=16384, C=64, fp32.
// scores[b,q,k] = sum_hw Q[b,hw,q]*K[b,hw,k]; attn=softmax_k; out[b,hw,q]=sum_k attn[b,q,k]*V[b,hw,k]
//
// ws: partial scores [B][SPLIT][64][64] fp32, then attn_t [B][64k][64q] fp32 (256 KB).
// SPLIT=64 (16 MiB) if ws allows, else 32 (8 MiB).
//
// Round-6: (a) scores with PER-WAVE PRIVATE staging and ZERO main-loop
// barriers (waves free-run -> VALU/LDS/HBM pipes overlap instead of
// summing; round-5 showed dur == sum-of-pipes due to barrier lockstep).
// (b) out with 8x8 lane tile (2x fewer LDS reads/FMA) and XOR-swizzled
// V tile (conflict-free with NO padding -> 80 KB -> 2 blocks/CU).

#define TILE_ROWS 32

// ---------------- Kernel A: partial scores, per-wave private staging, barrier-free main loop ----------------
// Wave w consumes ONLY rows r = 4i+w of each 32-row tile (for both Q and K),
// so staging is private per wave: 8 rows x (Q,K) = 4 KB slice, double-
// buffered. Per tile per wave: 4 global float4 loads (issued 1 tile ahead),
// 4 ds_writes, 32 ds_reads, 512 FMAs. No __syncthreads until the epilogue
// cross-wave reduction (unchanged, proven).
template <int SPLIT>
__global__ __launch_bounds__(256) void scores_kernel(
    const float* __restrict__ Q, const float* __restrict__ K,
    float* __restrict__ partial) {
  constexpr int CH = 16384 / SPLIT;       // rows per split chunk
  constexpr int NT = CH / TILE_ROWS;      // tile iterations
  const int bs = blockIdx.x;              // b * SPLIT + s
  const int b = bs / SPLIT;
  const int s = bs % SPLIT;
  const int tid = threadIdx.x;
  const int w = tid >> 6;                 // wave 0..3
  const int l = tid & 63;
  const int q0 = (l >> 3) * 8;            // 8 q per lane
  const int k0 = (l & 7) * 8;             // 8 k per lane

  __shared__ union {
    float4 buf[4][2][256];                // per-wave double-buffered: q quads [0..127], k quads [128..255]; 32 KB
    float red[2][4096];                   // 32 KB cross-wave reduction (epilogue only)
  } lds;

  float acc[8][8];
#pragma unroll
  for (int i = 0; i < 8; ++i)
#pragma unroll
    for (int j = 0; j < 8; ++j) acc[i][j] = 0.f;

  const float4* Qg = (const float4*)(Q + ((size_t)b * 16384 + (size_t)s * CH) * 64);
  const float4* Kg = (const float4*)(K + ((size_t)b * 16384 + (size_t)s * CH) * 64);

  // Per-lane staging map: linear quad n (0..127) <-> (row i=n>>4, quad c=n&15);
  // buf row i holds global row t*32 + 4i + w. Lane stages n=l and n=64+l.
  const int i0 = l >> 4;                  // 0..3
  const int c0 = l & 15;                  // 0..15
  const int gq0 = (4 * i0 + w) * 16 + c0;       // global quad for n = l
  const int gq1 = gq0 + 256;                    // global quad for n = 64+l (rows +16)

  // prologue: stage tile 0 into buffer 0 (private, no barrier)
  lds.buf[w][0][l]       = Qg[gq0];
  lds.buf[w][0][64 + l]  = Qg[gq1];
  lds.buf[w][0][128 + l] = Kg[gq0];
  lds.buf[w][0][192 + l] = Kg[gq1];

  for (int t = 0; t < NT; ++t) {
    const int cb = t & 1;

    // issue next tile's global loads (latency hides under this tile's FMAs)
    float4 pq0, pq1, pk0, pk1;
    if (t + 1 < NT) {
      pq0 = Qg[(t + 1) * 512 + gq0];
      pq1 = Qg[(t + 1) * 512 + gq1];
      pk0 = Kg[(t + 1) * 512 + gq0];
      pk1 = Kg[(t + 1) * 512 + gq1];
    }

    const float4* qp = lds.buf[w][cb];
    const float4* kp = lds.buf[w][cb] + 128;
#pragma unroll
    for (int i = 0; i < 8; ++i) {         // buf row i = global row t*32 + 4i + w
      float4 qa = qp[i * 16 + (q0 >> 2)];
      float4 qb = qp[i * 16 + (q0 >> 2) + 1];
      float4 ka = kp[i * 16 + (k0 >> 2)];
      float4 kb = kp[i * 16 + (k0 >> 2) + 1];
      float qv[8] = {qa.x, qa.y, qa.z, qa.w, qb.x, qb.y, qb.z, qb.w};
      float kv[8] = {ka.x, ka.y, ka.z, ka.w, kb.x, kb.y, kb.z, kb.w};
#pragma unroll
      for (int ii = 0; ii < 8; ++ii)
#pragma unroll
        for (int jj = 0; jj < 8; ++jj)
          acc[ii][jj] += qv[ii] * kv[jj];
    }

    // write the prefetched tile into the other private buffer
    if (t + 1 < NT) {
      const int nb = (t + 1) & 1;
      lds.buf[w][nb][l]       = pq0;
      lds.buf[w][nb][64 + l]  = pq1;
      lds.buf[w][nb][128 + l] = pk0;
      lds.buf[w][nb][192 + l] = pk1;
    }
  }

  // ---- cross-wave reduction (PROVEN): waves 2,3 publish; 0,1 add; halves summed on store ----
  __syncthreads();                        // all waves done with buf before red overwrites it
  if (w >= 2) {
    float4* dst = (float4*)lds.red[w - 2];
#pragma unroll
    for (int i = 0; i < 8; ++i) {
      dst[(q0 + i) * 16 + (k0 >> 2)]     = make_float4(acc[i][0], acc[i][1], acc[i][2], acc[i][3]);
      dst[(q0 + i) * 16 + (k0 >> 2) + 1] = make_float4(acc[i][4], acc[i][5], acc[i][6], acc[i][7]);
    }
  }
  __syncthreads();
  if (w < 2) {
    float4* dst = (float4*)lds.red[w];
#pragma unroll
    for (int i = 0; i < 8; ++i) {
      float4 u = dst[(q0 + i) * 16 + (k0 >> 2)];
      float4 v = dst[(q0 + i) * 16 + (k0 >> 2) + 1];
      dst[(q0 + i) * 16 + (k0 >> 2)]     = make_float4(u.x + acc[i][0], u.y + acc[i][1], u.z + acc[i][2], u.w + acc[i][3]);
      dst[(q0 + i) * 16 + (k0 >> 2) + 1] = make_float4(v.x + acc[i][4], v.y + acc[i][5], v.z + acc[i][6], v.w + acc[i][7]);
    }
  }
  __syncthreads();
  float4* p4 = (float4*)(partial + (size_t)bs * 4096);
  const float4* r0 = (const float4*)lds.red[0];
  const float4* r1 = (const float4*)lds.red[1];
#pragma unroll
  for (int c = 0; c < 4; ++c) {
    float4 x = r0[c * 256 + tid];
    float4 y = r1[c * 256 + tid];
    p4[c * 256 + tid] = make_float4(x.x + y.x, x.y + y.y, x.z + y.z, x.w + y.w);
  }
}

// ---------------- Kernel B: reduce partials + softmax, store TRANSPOSED attn_t[b][k][q] ----------------
// Block = (b, q-quad), 4 waves: wave w sums splits {w, w+4, ...}; 4-way LDS
// combine; wave 0 does the 16-lane shuffle softmax + transposed store.
template <int SPLIT>
__global__ __launch_bounds__(256) void softmax_kernel(
    const float* __restrict__ partial, float* __restrict__ attn_t) {
  const int blk = blockIdx.x;           // b*16 + qquad
  const int b = blk >> 4;
  const int q0 = (blk & 15) * 4;
  const int tid = threadIdx.x;
  const int w = tid >> 6;
  const int l = tid & 63;
  const int ql = l >> 4;                // q = q0+ql
  const int k4 = l & 15;                // float4 column

  __shared__ float4 red4[4][64];        // 4 KB

  const float4* P = (const float4*)partial;
  float4 v = make_float4(0.f, 0.f, 0.f, 0.f);
  for (int s = w; s < SPLIT; s += 4) {
    float4 t = P[((size_t)(b * SPLIT + s) * 64 + q0 + ql) * 16 + k4];
    v.x += t.x; v.y += t.y; v.z += t.z; v.w += t.w;
  }
  red4[w][l] = v;
  __syncthreads();
  if (w != 0) return;

  float4 v1 = red4[1][l], v2 = red4[2][l], v3 = red4[3][l];
  v.x += v1.x + v2.x + v3.x;
  v.y += v1.y + v2.y + v3.y;
  v.z += v1.z + v2.z + v3.z;
  v.w += v1.w + v2.w + v3.w;

  float m = fmaxf(fmaxf(v.x, v.y), fmaxf(v.z, v.w));
#pragma unroll
  for (int off = 8; off > 0; off >>= 1)
    m = fmaxf(m, __shfl_xor(m, off, 64));   // reduce across the 16 lanes sharing q
  float4 e = make_float4(__expf(v.x - m), __expf(v.y - m), __expf(v.z - m), __expf(v.w - m));
  float sum = e.x + e.y + e.z + e.w;
#pragma unroll
  for (int off = 8; off > 0; off >>= 1)
    sum += __shfl_xor(sum, off, 64);
  const float inv = 1.f / sum;

  float* A = attn_t + (size_t)b * 4096;   // [k][q]
  A[(4 * k4 + 0) * 64 + q0 + ql] = e.x * inv;
  A[(4 * k4 + 1) * 64 + q0 + ql] = e.y * inv;
  A[(4 * k4 + 2) * 64 + q0 + ql] = e.z * inv;
  A[(4 * k4 + 3) * 64 + q0 + ql] = e.w * inv;
}

// ---------------- Kernel C: out = V * attn_t, 8x8 lane tile, XOR-swizzled V (no pad) ----------------
// Block = 256 rows x 64 q, 4 waves; wave w owns rows w*64..w*64+63. Lane
// (rg=l>>3, qg=l&7): rows {rg+8i}, q cols {4qg..4qg+3} u {32+4qg..35+4qg}.
// V LDS quad index = row*16 + (k4 ^ (row&7)) -> the 8 rg-rows of a read hit
// 8 distinct bank-quads (T2 swizzle, zero padding): V 64 KB + A 16 KB =
// 80 KB = exactly 2 blocks/CU. Per k4 per wave: 16 b128 reads / 256 FMAs
// (2x the FMA/read of round-1's 8x4 tile -> LDS floor 31 -> 20.5 us).
// One barrier total, then free-running.
__global__ __launch_bounds__(256) void out_kernel(
    const float* __restrict__ V, const float* __restrict__ attn_t,
    float* __restrict__ out) {
  const int b = blockIdx.x >> 6;        // 64 tiles of 256 rows per batch
  const int tile = blockIdx.x & 63;
  const int tid = threadIdx.x;
  const int w = tid >> 6;
  const int l = tid & 63;
  const int rg = l >> 3;                // 0..7
  const int qg = l & 7;                 // 0..7

  __shared__ float4 Vl[256 * 16];       // swizzled, 64 KB
  __shared__ float4 Al[64 * 16];        // attn_t[k][q] row-major, 16 KB

  const float4* Vg = (const float4*)(V + ((size_t)b * 16384 + (size_t)tile * 256) * 64);
#pragma unroll
  for (int u = 0; u < 16; ++u) {
    const int n = u * 256 + tid;        // linear quad 0..4095 of the 256x64 tile
    const int r = n >> 4, c = n & 15;
    Vl[(r << 4) | (c ^ (r & 7))] = Vg[n];
  }
  const float4* Ag = (const float4*)(attn_t + (size_t)b * 4096);
#pragma unroll
  for (int u = 0; u < 4; ++u)
    Al[u * 256 + tid] = Ag[u * 256 + tid];
  __syncthreads();

  float acc[8][8];
#pragma unroll
  for (int i = 0; i < 8; ++i)
#pragma unroll
    for (int j = 0; j < 8; ++j) acc[i][j] = 0.f;

#pragma unroll 2
  for (int k4 = 0; k4 < 16; ++k4) {
    float4 alo[4], ahi[4];
#pragma unroll
    for (int j = 0; j < 4; ++j) {
      alo[j] = Al[(4 * k4 + j) * 16 + qg];        // A[4k4+j][4qg..4qg+3]
      ahi[j] = Al[(4 * k4 + j) * 16 + 8 + qg];    // A[4k4+j][32+4qg..35+4qg]
    }
#pragma unroll
    for (int i = 0; i < 8; ++i) {
      const int row = (w << 6) + rg + 8 * i;      // row&7 == rg
      const float4 v = Vl[(row << 4) | (k4 ^ rg)];// V[row][4k4..4k4+3]
      acc[i][0] += v.x * alo[0].x + v.y * alo[1].x + v.z * alo[2].x + v.w * alo[3].x;
      acc[i][1] += v.x * alo[0].y + v.y * alo[1].y + v.z * alo[2].y + v.w * alo[3].y;
      acc[i][2] += v.x * alo[0].z + v.y * alo[1].z + v.z * alo[2].z + v.w * alo[3].z;
      acc[i][3] += v.x * alo[0].w + v.y * alo[1].w + v.z * alo[2].w + v.w * alo[3].w;
      acc[i][4] += v.x * ahi[0].x + v.y * ahi[1].x + v.z * ahi[2].x + v.w * ahi[3].x;
      acc[i][5] += v.x * ahi[0].y + v.y * ahi[1].y + v.z * ahi[2].y + v.w * ahi[3].y;
      acc[i][6] += v.x * ahi[0].z + v.y * ahi[1].z + v.z * ahi[2].z + v.w * ahi[3].z;
      acc[i][7] += v.x * ahi[0].w + v.y * ahi[1].w + v.z * ahi[2].w + v.w * ahi[3].w;
    }
  }

  float4* og = (float4*)(out + ((size_t)b * 16384 + (size_t)tile * 256) * 64);
#pragma unroll
  for (int i = 0; i < 8; ++i) {
    const int row = (w << 6) + rg + 8 * i;
    og[row * 16 + qg]     = make_float4(acc[i][0], acc[i][1], acc[i][2], acc[i][3]);
    og[row * 16 + 8 + qg] = make_float4(acc[i][4], acc[i][5], acc[i][6], acc[i][7]);
  }
}

extern "C" void kernel_launch(void* const* d_in, const int* in_sizes, int n_in,
                              void* d_out, int out_size, void* d_ws, size_t ws_size,
                              hipStream_t stream) {
  const float* Q = (const float*)d_in[0];
  const float* K = (const float*)d_in[1];
  const float* V = (const float*)d_in[2];
  float* out = (float*)d_out;

  const size_t need64 = (size_t)16 * 64 * 4096 * 4 + (size_t)16 * 4096 * 4;  // 16 MiB + 256 KiB

  if (ws_size >= need64) {
    float* partial = (float*)d_ws;
    float* attn_t = partial + (size_t)16 * 64 * 4096;
    scores_kernel<64><<<16 * 64, 256, 0, stream>>>(Q, K, partial);
    softmax_kernel<64><<<16 * 16, 256, 0, stream>>>(partial, attn_t);
    out_kernel<<<16 * 64, 256, 0, stream>>>(V, attn_t, out);
  } else {
    float* partial = (float*)d_ws;
    float* attn_t = partial + (size_t)16 * 32 * 4096;
    scores_kernel<32><<<16 * 32, 256, 0, stream>>>(Q, K, partial);
    softmax_kernel<32><<<16 * 16, 256, 0, stream>>>(partial, attn_t);
    out_kernel<<<16 * 64, 256, 0, stream>>>(V, attn_t, out);
  }
}